// Round 1
// baseline (320.752 us; speedup 1.0000x reference)
//
#include <hip/hip_runtime.h>

#define NODES 40000
#define INDIM 128
#define HID 64

// ---------------------------------------------------------------- CSR build

__global__ __launch_bounds__(256) void k_zero_deg(int* __restrict__ deg, int n) {
    int i = blockIdx.x * 256 + threadIdx.x;
    if (i < n) deg[i] = 0;
}

__global__ __launch_bounds__(256) void k_count(const int* __restrict__ dst,
                                               int* __restrict__ deg, int E) {
    int e = blockIdx.x * 256 + threadIdx.x;
    if (e < E) atomicAdd(&deg[dst[e]], 1);
}

// Single-block exclusive scan over deg[0..n) -> offs/cursor; offs[n] = total.
__global__ __launch_bounds__(1024) void k_scan(const int* __restrict__ deg,
                                               int* __restrict__ offs,
                                               int* __restrict__ cursor, int n) {
    __shared__ int wsum[16];
    __shared__ int s_carry;
    const int tid  = threadIdx.x;
    const int lane = tid & 63;
    const int w    = tid >> 6;
    if (tid == 0) s_carry = 0;
    __syncthreads();
    for (int base = 0; base < n; base += 1024) {
        int i = base + tid;
        int v = (i < n) ? deg[i] : 0;
        int s = v;
        #pragma unroll
        for (int off = 1; off < 64; off <<= 1) {
            int t = __shfl_up(s, off, 64);
            if (lane >= off) s += t;
        }
        if (lane == 63) wsum[w] = s;
        __syncthreads();
        int carry = s_carry;
        int wbase = 0;
        for (int ww = 0; ww < w; ++ww) wbase += wsum[ww];
        int excl = carry + wbase + (s - v);
        if (i < n) { offs[i] = excl; cursor[i] = excl; }
        __syncthreads();
        if (tid == 1023) s_carry = carry + wbase + s;   // running total
        __syncthreads();
    }
    if (threadIdx.x == 0) offs[n] = s_carry;
}

__global__ __launch_bounds__(256) void k_scatter(const int* __restrict__ src,
                                                 const int* __restrict__ dst,
                                                 int* __restrict__ cursor,
                                                 int* __restrict__ sorted_src, int E) {
    int e = blockIdx.x * 256 + threadIdx.x;
    if (e < E) {
        int p = atomicAdd(&cursor[dst[e]], 1);
        sorted_src[p] = src[e];
    }
}

// ------------------------------------------------------- weight transposes

// W1: [64][128] row-major -> WT1 [128][64]; W2: [64][64] -> WT2 [64][64]
__global__ __launch_bounds__(256) void k_transpose(
    const float* __restrict__ W1l, const float* __restrict__ W1r,
    const float* __restrict__ W2l, const float* __restrict__ W2r,
    float* __restrict__ WT1l, float* __restrict__ WT1r,
    float* __restrict__ WT2l, float* __restrict__ WT2r) {
    int tid = blockIdx.x * 256 + threadIdx.x;
    if (tid < 64 * 128) {
        int j = tid >> 7, k = tid & 127;
        WT1l[k * 64 + j] = W1l[tid];
        WT1r[k * 64 + j] = W1r[tid];
    }
    if (tid < 64 * 64) {
        int j = tid >> 6, k = tid & 63;
        WT2l[k * 64 + j] = W2l[tid];
        WT2r[k * 64 + j] = W2r[tid];
    }
}

// ------------------------------------------------------------ dual GEMM
// P = A @ Wl.T, Q = A @ Wr.T, with WT* pre-transposed to [K][64].
// Block: 256 threads computes a 64-node x 64-out tile for BOTH matrices.
// Thread (tx,ty) = 4 outs x 4 nodes register tile.

template <int K>
__global__ __launch_bounds__(256) void k_gemm_dual(
    const float* __restrict__ A,      // [M][K]
    const float* __restrict__ WTl,    // [K][64]
    const float* __restrict__ WTr,    // [K][64]
    float* __restrict__ P,            // [M][64]
    float* __restrict__ Q) {          // [M][64]
    __shared__ float As[64][K + 1];   // +1 pad: bank-conflict-free strided reads
    const int tid = threadIdx.x;
    const int bm  = blockIdx.x * 64;

    // stage A tile (float4, fully coalesced)
    for (int idx = tid; idx < 64 * (K / 4); idx += 256) {
        int row = idx / (K / 4), kq = idx % (K / 4);
        const float4 v = ((const float4*)A)[(size_t)(bm + row) * (K / 4) + kq];
        As[row][kq * 4 + 0] = v.x;
        As[row][kq * 4 + 1] = v.y;
        As[row][kq * 4 + 2] = v.z;
        As[row][kq * 4 + 3] = v.w;
    }
    __syncthreads();

    const int tx = tid & 15, ty = tid >> 4;
    const int j0 = tx * 4, n0 = ty * 4;
    float accl[4][4] = {};
    float accr[4][4] = {};

    #pragma unroll 8
    for (int k = 0; k < K; ++k) {
        float a[4];
        #pragma unroll
        for (int i = 0; i < 4; ++i) a[i] = As[n0 + i][k];
        const float4 blv = ((const float4*)WTl)[k * 16 + tx];  // L1-resident broadcast
        const float4 brv = ((const float4*)WTr)[k * 16 + tx];
        const float bl[4] = {blv.x, blv.y, blv.z, blv.w};
        const float br[4] = {brv.x, brv.y, brv.z, brv.w};
        #pragma unroll
        for (int i = 0; i < 4; ++i) {
            #pragma unroll
            for (int j = 0; j < 4; ++j) {
                accl[i][j] += a[i] * bl[j];
                accr[i][j] += a[i] * br[j];
            }
        }
    }

    #pragma unroll
    for (int i = 0; i < 4; ++i) {
        int m = bm + n0 + i;
        float4 vl = make_float4(accl[i][0], accl[i][1], accl[i][2], accl[i][3]);
        float4 vr = make_float4(accr[i][0], accr[i][1], accr[i][2], accr[i][3]);
        ((float4*)P)[(size_t)m * 16 + tx] = vl;
        ((float4*)Q)[(size_t)m * 16 + tx] = vr;
    }
}

// ---------------------------------------------------------- aggregation
// One wave per dst node; lane = feature dim (64).
// out[n][d] = (sum_{s in N(n)} P[s][d]) / max(cnt,1) + bias[d] + Q[n][d]  (opt ReLU)

__global__ __launch_bounds__(256) void k_agg(
    const float* __restrict__ P, const float* __restrict__ Q,
    const float* __restrict__ bias,
    const int* __restrict__ offs, const int* __restrict__ sorted_src,
    float* __restrict__ out, int n, int relu) {
    const int wid  = (blockIdx.x * 256 + threadIdx.x) >> 6;  // node id
    const int lane = threadIdx.x & 63;
    if (wid >= n) return;
    const int s0 = offs[wid], s1 = offs[wid + 1];
    float acc = 0.f;
    int e = s0;
    for (; e + 3 < s1; e += 4) {   // 4 gathers in flight for latency hiding
        int sa = sorted_src[e + 0], sb = sorted_src[e + 1];
        int sc = sorted_src[e + 2], sd = sorted_src[e + 3];
        float va = P[(size_t)sa * 64 + lane];
        float vb = P[(size_t)sb * 64 + lane];
        float vc = P[(size_t)sc * 64 + lane];
        float vd = P[(size_t)sd * 64 + lane];
        acc += va + vb + vc + vd;
    }
    for (; e < s1; ++e) acc += P[(size_t)sorted_src[e] * 64 + lane];

    float cnt = (float)(s1 - s0);
    float v = acc * (1.0f / fmaxf(cnt, 1.0f)) + bias[lane] + Q[(size_t)wid * 64 + lane];
    if (relu) v = fmaxf(v, 0.f);
    out[(size_t)wid * 64 + lane] = v;
}

// ---------------------------------------------------------------- launcher

extern "C" void kernel_launch(void* const* d_in, const int* in_sizes, int n_in,
                              void* d_out, int out_size, void* d_ws, size_t ws_size,
                              hipStream_t stream) {
    const float* x    = (const float*)d_in[0];
    const int*   edge = (const int*)d_in[1];
    const float* W1l  = (const float*)d_in[2];
    const float* b1l  = (const float*)d_in[3];
    const float* W1r  = (const float*)d_in[4];
    const float* W2l  = (const float*)d_in[5];
    const float* b2l  = (const float*)d_in[6];
    const float* W2r  = (const float*)d_in[7];

    const int N = in_sizes[0] / INDIM;   // 40000
    const int E = in_sizes[1] / 2;       // 640000
    const int* src = edge;
    const int* dst = edge + E;

    // workspace carve (all 16B aligned)
    char* w = (char*)d_ws;
    float* P    = (float*)w; w += (size_t)N * 64 * 4;
    float* Q    = (float*)w; w += (size_t)N * 64 * 4;
    float* H    = (float*)w; w += (size_t)N * 64 * 4;
    float* WT1l = (float*)w; w += 128 * 64 * 4;
    float* WT1r = (float*)w; w += 128 * 64 * 4;
    float* WT2l = (float*)w; w += 64 * 64 * 4;
    float* WT2r = (float*)w; w += 64 * 64 * 4;
    int* deg    = (int*)w;   w += (size_t)N * 4;
    int* cursor = (int*)w;   w += (size_t)N * 4;
    int* sorted = (int*)w;   w += (size_t)E * 4;
    int* offs   = (int*)w;   w += (size_t)(N + 1) * 4;

    float* zout = (float*)d_out;

    const int gE = (E + 255) / 256;
    const int gN = (N + 255) / 256;

    k_transpose<<<32, 256, 0, stream>>>(W1l, W1r, W2l, W2r, WT1l, WT1r, WT2l, WT2r);
    k_zero_deg<<<gN, 256, 0, stream>>>(deg, N);
    k_count<<<gE, 256, 0, stream>>>(dst, deg, E);
    k_scan<<<1, 1024, 0, stream>>>(deg, offs, cursor, N);
    k_scatter<<<gE, 256, 0, stream>>>(src, dst, cursor, sorted, E);

    // layer 1: project-then-aggregate (linearity of mean)
    k_gemm_dual<INDIM><<<N / 64, 256, 0, stream>>>(x, WT1l, WT1r, P, Q);
    k_agg<<<(N * 64 + 255) / 256, 256, 0, stream>>>(P, Q, b1l, offs, sorted, H, N, 1);

    // layer 2
    k_gemm_dual<HID><<<N / 64, 256, 0, stream>>>(H, WT2l, WT2r, P, Q);
    k_agg<<<(N * 64 + 255) / 256, 256, 0, stream>>>(P, Q, b2l, offs, sorted, zout, N, 0);
}

// Round 2
// 283.326 us; speedup vs baseline: 1.1321x; 1.1321x over previous
//
#include <hip/hip_runtime.h>

#define NODES 40000
#define INDIM 128
#define HID 64

// ---------------------------------------------------------------- CSR build

__global__ __launch_bounds__(256) void k_count(const int* __restrict__ dst,
                                               int* __restrict__ deg, int E) {
    int e = blockIdx.x * 256 + threadIdx.x;
    if (e < E) atomicAdd(&deg[dst[e]], 1);
}

// --- hierarchical exclusive scan over deg[0..n), B = ceil(n/256) <= 256 ----
// phase 1: per-block exclusive scan -> offs (local), block total -> partials[b]
__global__ __launch_bounds__(256) void k_scan_local(const int* __restrict__ deg,
                                                    int* __restrict__ offs,
                                                    int* __restrict__ partials, int n) {
    __shared__ int wsum[4];
    const int tid = threadIdx.x;
    const int i = blockIdx.x * 256 + tid;
    const int lane = tid & 63, w = tid >> 6;
    int v = (i < n) ? deg[i] : 0;
    int s = v;
    #pragma unroll
    for (int off = 1; off < 64; off <<= 1) {
        int t = __shfl_up(s, off, 64);
        if (lane >= off) s += t;
    }
    if (lane == 63) wsum[w] = s;
    __syncthreads();
    int wbase = 0;
    #pragma unroll
    for (int ww = 0; ww < 3; ++ww) wbase += (ww < w) ? wsum[ww] : 0;
    if (i < n) offs[i] = wbase + s - v;
    if (tid == 255) partials[blockIdx.x] = wbase + s;
}

// phase 2: single block scans partials[0..B) exclusively; grand total -> *total
__global__ __launch_bounds__(256) void k_scan_partials(int* __restrict__ partials,
                                                       int* __restrict__ total, int B) {
    __shared__ int wsum[4];
    const int tid = threadIdx.x;
    const int lane = tid & 63, w = tid >> 6;
    int v = (tid < B) ? partials[tid] : 0;
    int s = v;
    #pragma unroll
    for (int off = 1; off < 64; off <<= 1) {
        int t = __shfl_up(s, off, 64);
        if (lane >= off) s += t;
    }
    if (lane == 63) wsum[w] = s;
    __syncthreads();
    int wbase = 0;
    #pragma unroll
    for (int ww = 0; ww < 3; ++ww) wbase += (ww < w) ? wsum[ww] : 0;
    if (tid < B) partials[tid] = wbase + s - v;
    if (tid == 255) *total = wbase + s;
}

// phase 3: add block offsets; also fill cursor
__global__ __launch_bounds__(256) void k_scan_add(const int* __restrict__ partials,
                                                  int* __restrict__ offs,
                                                  int* __restrict__ cursor, int n) {
    int i = blockIdx.x * 256 + threadIdx.x;
    if (i < n) {
        int o = offs[i] + partials[blockIdx.x];
        offs[i] = o;
        cursor[i] = o;
    }
}

__global__ __launch_bounds__(256) void k_scatter(const int* __restrict__ src,
                                                 const int* __restrict__ dst,
                                                 int* __restrict__ cursor,
                                                 int* __restrict__ sorted_src, int E) {
    int e = blockIdx.x * 256 + threadIdx.x;
    if (e < E) {
        int p = atomicAdd(&cursor[dst[e]], 1);
        sorted_src[p] = src[e];
    }
}

// ------------------------------------------------------- weight transposes

__global__ __launch_bounds__(256) void k_transpose(
    const float* __restrict__ W1l, const float* __restrict__ W1r,
    const float* __restrict__ W2l, const float* __restrict__ W2r,
    float* __restrict__ WT1l, float* __restrict__ WT1r,
    float* __restrict__ WT2l, float* __restrict__ WT2r) {
    int tid = blockIdx.x * 256 + threadIdx.x;
    if (tid < 64 * 128) {
        int j = tid >> 7, k = tid & 127;
        WT1l[k * 64 + j] = W1l[tid];
        WT1r[k * 64 + j] = W1r[tid];
    }
    if (tid < 64 * 64) {
        int j = tid >> 6, k = tid & 63;
        WT2l[k * 64 + j] = W2l[tid];
        WT2r[k * 64 + j] = W2r[tid];
    }
}

// ------------------------------------------------------------ dual GEMM

template <int K>
__global__ __launch_bounds__(256) void k_gemm_dual(
    const float* __restrict__ A,      // [M][K]
    const float* __restrict__ WTl,    // [K][64]
    const float* __restrict__ WTr,    // [K][64]
    float* __restrict__ P,            // [M][64]
    float* __restrict__ Q) {          // [M][64]
    __shared__ float As[64][K + 1];
    const int tid = threadIdx.x;
    const int bm  = blockIdx.x * 64;

    for (int idx = tid; idx < 64 * (K / 4); idx += 256) {
        int row = idx / (K / 4), kq = idx % (K / 4);
        const float4 v = ((const float4*)A)[(size_t)(bm + row) * (K / 4) + kq];
        As[row][kq * 4 + 0] = v.x;
        As[row][kq * 4 + 1] = v.y;
        As[row][kq * 4 + 2] = v.z;
        As[row][kq * 4 + 3] = v.w;
    }
    __syncthreads();

    const int tx = tid & 15, ty = tid >> 4;
    const int n0 = ty * 4;
    float accl[4][4] = {};
    float accr[4][4] = {};

    #pragma unroll 8
    for (int k = 0; k < K; ++k) {
        float a[4];
        #pragma unroll
        for (int i = 0; i < 4; ++i) a[i] = As[n0 + i][k];
        const float4 blv = ((const float4*)WTl)[k * 16 + tx];
        const float4 brv = ((const float4*)WTr)[k * 16 + tx];
        const float bl[4] = {blv.x, blv.y, blv.z, blv.w};
        const float br[4] = {brv.x, brv.y, brv.z, brv.w};
        #pragma unroll
        for (int i = 0; i < 4; ++i) {
            #pragma unroll
            for (int j = 0; j < 4; ++j) {
                accl[i][j] += a[i] * bl[j];
                accr[i][j] += a[i] * br[j];
            }
        }
    }

    #pragma unroll
    for (int i = 0; i < 4; ++i) {
        int m = bm + n0 + i;
        float4 vl = make_float4(accl[i][0], accl[i][1], accl[i][2], accl[i][3]);
        float4 vr = make_float4(accr[i][0], accr[i][1], accr[i][2], accr[i][3]);
        ((float4*)P)[(size_t)m * 16 + tx] = vl;
        ((float4*)Q)[(size_t)m * 16 + tx] = vr;
    }
}

// ---------------------------------------------------------- aggregation

__global__ __launch_bounds__(256) void k_agg(
    const float* __restrict__ P, const float* __restrict__ Q,
    const float* __restrict__ bias,
    const int* __restrict__ offs, const int* __restrict__ sorted_src,
    float* __restrict__ out, int n, int relu) {
    const int wid  = (blockIdx.x * 256 + threadIdx.x) >> 6;
    const int lane = threadIdx.x & 63;
    if (wid >= n) return;
    const int s0 = offs[wid], s1 = offs[wid + 1];
    float acc = 0.f;
    int e = s0;
    for (; e + 3 < s1; e += 4) {
        int sa = sorted_src[e + 0], sb = sorted_src[e + 1];
        int sc = sorted_src[e + 2], sd = sorted_src[e + 3];
        float va = P[(size_t)sa * 64 + lane];
        float vb = P[(size_t)sb * 64 + lane];
        float vc = P[(size_t)sc * 64 + lane];
        float vd = P[(size_t)sd * 64 + lane];
        acc += va + vb + vc + vd;
    }
    for (; e < s1; ++e) acc += P[(size_t)sorted_src[e] * 64 + lane];

    float cnt = (float)(s1 - s0);
    float v = acc * (1.0f / fmaxf(cnt, 1.0f)) + bias[lane] + Q[(size_t)wid * 64 + lane];
    if (relu) v = fmaxf(v, 0.f);
    out[(size_t)wid * 64 + lane] = v;
}

// ---------------------------------------------------------------- launcher

extern "C" void kernel_launch(void* const* d_in, const int* in_sizes, int n_in,
                              void* d_out, int out_size, void* d_ws, size_t ws_size,
                              hipStream_t stream) {
    const float* x    = (const float*)d_in[0];
    const int*   edge = (const int*)d_in[1];
    const float* W1l  = (const float*)d_in[2];
    const float* b1l  = (const float*)d_in[3];
    const float* W1r  = (const float*)d_in[4];
    const float* W2l  = (const float*)d_in[5];
    const float* b2l  = (const float*)d_in[6];
    const float* W2r  = (const float*)d_in[7];

    const int N = in_sizes[0] / INDIM;   // 40000
    const int E = in_sizes[1] / 2;       // 640000
    const int* src = edge;
    const int* dst = edge + E;

    // workspace carve (all 16B aligned)
    char* w = (char*)d_ws;
    float* P    = (float*)w; w += (size_t)N * 64 * 4;
    float* Q    = (float*)w; w += (size_t)N * 64 * 4;
    float* H    = (float*)w; w += (size_t)N * 64 * 4;
    float* WT1l = (float*)w; w += 128 * 64 * 4;
    float* WT1r = (float*)w; w += 128 * 64 * 4;
    float* WT2l = (float*)w; w += 64 * 64 * 4;
    float* WT2r = (float*)w; w += 64 * 64 * 4;
    int* deg    = (int*)w;   w += (size_t)N * 4;
    int* cursor = (int*)w;   w += (size_t)N * 4;
    int* sorted = (int*)w;   w += (size_t)E * 4;
    int* offs   = (int*)w;   w += (size_t)(N + 1) * 4;
    int* partials = (int*)w; w += 256 * 4;

    float* zout = (float*)d_out;

    const int gE = (E + 255) / 256;
    const int gN = (N + 255) / 256;   // 157 blocks, <= 256

    k_transpose<<<32, 256, 0, stream>>>(W1l, W1r, W2l, W2r, WT1l, WT1r, WT2l, WT2r);
    hipMemsetAsync(deg, 0, (size_t)N * 4, stream);
    k_count<<<gE, 256, 0, stream>>>(dst, deg, E);
    k_scan_local<<<gN, 256, 0, stream>>>(deg, offs, partials, N);
    k_scan_partials<<<1, 256, 0, stream>>>(partials, offs + N, gN);
    k_scan_add<<<gN, 256, 0, stream>>>(partials, offs, cursor, N);
    k_scatter<<<gE, 256, 0, stream>>>(src, dst, cursor, sorted, E);

    // layer 1: project-then-aggregate (linearity of mean)
    k_gemm_dual<INDIM><<<N / 64, 256, 0, stream>>>(x, WT1l, WT1r, P, Q);
    k_agg<<<(N * 64 + 255) / 256, 256, 0, stream>>>(P, Q, b1l, offs, sorted, H, N, 1);

    // layer 2
    k_gemm_dual<HID><<<N / 64, 256, 0, stream>>>(H, WT2l, WT2r, P, Q);
    k_agg<<<(N * 64 + 255) / 256, 256, 0, stream>>>(P, Q, b2l, offs, sorted, zout, N, 0);
}

// Round 3
// 273.175 us; speedup vs baseline: 1.1742x; 1.0372x over previous
//
#include <hip/hip_runtime.h>

#define NODES 40000
#define INDIM 128
#define HID 64

// bf16 <-> f32 helpers (RNE; values are finite, no NaN handling needed)
__device__ __forceinline__ float bf2f(unsigned short u) {
    union { unsigned int i; float f; } c; c.i = ((unsigned int)u) << 16; return c.f;
}
__device__ __forceinline__ unsigned short f2bf(float f) {
    union { float f; unsigned int i; } c; c.f = f;
    unsigned int u = c.i;
    return (unsigned short)((u + 0x7FFFu + ((u >> 16) & 1u)) >> 16);
}

// ---------------------------------------------------------------- CSR build

__global__ __launch_bounds__(256) void k_count(const int* __restrict__ dst,
                                               int* __restrict__ deg, int E) {
    int e = blockIdx.x * 256 + threadIdx.x;
    if (e < E) atomicAdd(&deg[dst[e]], 1);
}

// phase 1: per-block exclusive scan -> offs (local), block total -> partials[b]
__global__ __launch_bounds__(256) void k_scan_local(const int* __restrict__ deg,
                                                    int* __restrict__ offs,
                                                    int* __restrict__ partials, int n) {
    __shared__ int wsum[4];
    const int tid = threadIdx.x;
    const int i = blockIdx.x * 256 + tid;
    const int lane = tid & 63, w = tid >> 6;
    int v = (i < n) ? deg[i] : 0;
    int s = v;
    #pragma unroll
    for (int off = 1; off < 64; off <<= 1) {
        int t = __shfl_up(s, off, 64);
        if (lane >= off) s += t;
    }
    if (lane == 63) wsum[w] = s;
    __syncthreads();
    int wbase = 0;
    #pragma unroll
    for (int ww = 0; ww < 3; ++ww) wbase += (ww < w) ? wsum[ww] : 0;
    if (i < n) offs[i] = wbase + s - v;
    if (tid == 255) partials[blockIdx.x] = wbase + s;
}

// phase 2: single block scans partials[0..B) exclusively; grand total -> *total
__global__ __launch_bounds__(256) void k_scan_partials(int* __restrict__ partials,
                                                       int* __restrict__ total, int B) {
    __shared__ int wsum[4];
    const int tid = threadIdx.x;
    const int lane = tid & 63, w = tid >> 6;
    int v = (tid < B) ? partials[tid] : 0;
    int s = v;
    #pragma unroll
    for (int off = 1; off < 64; off <<= 1) {
        int t = __shfl_up(s, off, 64);
        if (lane >= off) s += t;
    }
    if (lane == 63) wsum[w] = s;
    __syncthreads();
    int wbase = 0;
    #pragma unroll
    for (int ww = 0; ww < 3; ++ww) wbase += (ww < w) ? wsum[ww] : 0;
    if (tid < B) partials[tid] = wbase + s - v;
    if (tid == 255) *total = wbase + s;
}

// phase 3: add block offsets; also fill cursor
__global__ __launch_bounds__(256) void k_scan_add(const int* __restrict__ partials,
                                                  int* __restrict__ offs,
                                                  int* __restrict__ cursor, int n) {
    int i = blockIdx.x * 256 + threadIdx.x;
    if (i < n) {
        int o = offs[i] + partials[blockIdx.x];
        offs[i] = o;
        cursor[i] = o;
    }
}

__global__ __launch_bounds__(256) void k_scatter(const int* __restrict__ src,
                                                 const int* __restrict__ dst,
                                                 int* __restrict__ cursor,
                                                 int* __restrict__ sorted_src, int E) {
    int e = blockIdx.x * 256 + threadIdx.x;
    if (e < E) {
        int p = atomicAdd(&cursor[dst[e]], 1);
        sorted_src[p] = src[e];
    }
}

// ------------------------------------------------------- weight transposes

__global__ __launch_bounds__(256) void k_transpose(
    const float* __restrict__ W1l, const float* __restrict__ W1r,
    const float* __restrict__ W2l, const float* __restrict__ W2r,
    float* __restrict__ WT1l, float* __restrict__ WT1r,
    float* __restrict__ WT2l, float* __restrict__ WT2r) {
    int tid = blockIdx.x * 256 + threadIdx.x;
    if (tid < 64 * 128) {
        int j = tid >> 7, k = tid & 127;
        WT1l[k * 64 + j] = W1l[tid];
        WT1r[k * 64 + j] = W1r[tid];
    }
    if (tid < 64 * 64) {
        int j = tid >> 6, k = tid & 63;
        WT2l[k * 64 + j] = W2l[tid];
        WT2r[k * 64 + j] = W2r[tid];
    }
}

// ------------------------------------------------------------ dual GEMM
// P (bf16) = A @ Wl.T, Q (f32) = A @ Wr.T; WT* pre-transposed to [K][64].

template <int K>
__global__ __launch_bounds__(256) void k_gemm_dual(
    const float* __restrict__ A,          // [M][K] f32
    const float* __restrict__ WTl,        // [K][64]
    const float* __restrict__ WTr,        // [K][64]
    unsigned short* __restrict__ Pb,      // [M][64] bf16
    float* __restrict__ Q) {              // [M][64] f32
    __shared__ float As[64][K + 1];
    const int tid = threadIdx.x;
    const int bm  = blockIdx.x * 64;

    for (int idx = tid; idx < 64 * (K / 4); idx += 256) {
        int row = idx / (K / 4), kq = idx % (K / 4);
        const float4 v = ((const float4*)A)[(size_t)(bm + row) * (K / 4) + kq];
        As[row][kq * 4 + 0] = v.x;
        As[row][kq * 4 + 1] = v.y;
        As[row][kq * 4 + 2] = v.z;
        As[row][kq * 4 + 3] = v.w;
    }
    __syncthreads();

    const int tx = tid & 15, ty = tid >> 4;
    const int n0 = ty * 4;
    float accl[4][4] = {};
    float accr[4][4] = {};

    #pragma unroll 8
    for (int k = 0; k < K; ++k) {
        float a[4];
        #pragma unroll
        for (int i = 0; i < 4; ++i) a[i] = As[n0 + i][k];
        const float4 blv = ((const float4*)WTl)[k * 16 + tx];
        const float4 brv = ((const float4*)WTr)[k * 16 + tx];
        const float bl[4] = {blv.x, blv.y, blv.z, blv.w};
        const float br[4] = {brv.x, brv.y, brv.z, brv.w};
        #pragma unroll
        for (int i = 0; i < 4; ++i) {
            #pragma unroll
            for (int j = 0; j < 4; ++j) {
                accl[i][j] += a[i] * bl[j];
                accr[i][j] += a[i] * br[j];
            }
        }
    }

    #pragma unroll
    for (int i = 0; i < 4; ++i) {
        int m = bm + n0 + i;
        ushort4 pv;
        pv.x = f2bf(accl[i][0]); pv.y = f2bf(accl[i][1]);
        pv.z = f2bf(accl[i][2]); pv.w = f2bf(accl[i][3]);
        ((ushort4*)Pb)[(size_t)m * 16 + tx] = pv;
        float4 vr = make_float4(accr[i][0], accr[i][1], accr[i][2], accr[i][3]);
        ((float4*)Q)[(size_t)m * 16 + tx] = vr;
    }
}

// ---------------------------------------------------------- aggregation
// One wave per dst node; lane = feature dim. Gathers bf16 P rows (128B/row),
// accumulates f32. 8 gathers in flight for latency hiding.

__global__ __launch_bounds__(256) void k_agg(
    const unsigned short* __restrict__ Pb, const float* __restrict__ Q,
    const float* __restrict__ bias,
    const int* __restrict__ offs, const int* __restrict__ sorted_src,
    float* __restrict__ out, int n, int relu) {
    const int wid  = (blockIdx.x * 256 + threadIdx.x) >> 6;
    const int lane = threadIdx.x & 63;
    if (wid >= n) return;
    const int s0 = offs[wid], s1 = offs[wid + 1];
    float acc = 0.f;
    int e = s0;
    for (; e + 7 < s1; e += 8) {
        int si[8];
        #pragma unroll
        for (int j = 0; j < 8; ++j) si[j] = sorted_src[e + j];
        float v[8];
        #pragma unroll
        for (int j = 0; j < 8; ++j) v[j] = bf2f(Pb[(size_t)si[j] * 64 + lane]);
        #pragma unroll
        for (int j = 0; j < 8; ++j) acc += v[j];
    }
    for (; e < s1; ++e) acc += bf2f(Pb[(size_t)sorted_src[e] * 64 + lane]);

    float cnt = (float)(s1 - s0);
    float v = acc * (1.0f / fmaxf(cnt, 1.0f)) + bias[lane] + Q[(size_t)wid * 64 + lane];
    if (relu) v = fmaxf(v, 0.f);
    out[(size_t)wid * 64 + lane] = v;
}

// ---------------------------------------------------------------- launcher

extern "C" void kernel_launch(void* const* d_in, const int* in_sizes, int n_in,
                              void* d_out, int out_size, void* d_ws, size_t ws_size,
                              hipStream_t stream) {
    const float* x    = (const float*)d_in[0];
    const int*   edge = (const int*)d_in[1];
    const float* W1l  = (const float*)d_in[2];
    const float* b1l  = (const float*)d_in[3];
    const float* W1r  = (const float*)d_in[4];
    const float* W2l  = (const float*)d_in[5];
    const float* b2l  = (const float*)d_in[6];
    const float* W2r  = (const float*)d_in[7];

    const int N = in_sizes[0] / INDIM;   // 40000
    const int E = in_sizes[1] / 2;       // 640000
    const int* src = edge;
    const int* dst = edge + E;

    // workspace carve (all 16B aligned)
    char* w = (char*)d_ws;
    unsigned short* Pb = (unsigned short*)w; w += (size_t)N * 64 * 2;
    float* Q    = (float*)w; w += (size_t)N * 64 * 4;
    float* H    = (float*)w; w += (size_t)N * 64 * 4;
    float* WT1l = (float*)w; w += 128 * 64 * 4;
    float* WT1r = (float*)w; w += 128 * 64 * 4;
    float* WT2l = (float*)w; w += 64 * 64 * 4;
    float* WT2r = (float*)w; w += 64 * 64 * 4;
    int* deg    = (int*)w;   w += (size_t)N * 4;
    int* cursor = (int*)w;   w += (size_t)N * 4;
    int* sorted = (int*)w;   w += (size_t)E * 4;
    int* offs   = (int*)w;   w += (size_t)(N + 1) * 4;
    int* partials = (int*)w; w += 256 * 4;

    float* zout = (float*)d_out;

    const int gE = (E + 255) / 256;
    const int gN = (N + 255) / 256;   // 157 blocks, <= 256

    k_transpose<<<32, 256, 0, stream>>>(W1l, W1r, W2l, W2r, WT1l, WT1r, WT2l, WT2r);
    hipMemsetAsync(deg, 0, (size_t)N * 4, stream);
    k_count<<<gE, 256, 0, stream>>>(dst, deg, E);
    k_scan_local<<<gN, 256, 0, stream>>>(deg, offs, partials, N);
    k_scan_partials<<<1, 256, 0, stream>>>(partials, offs + N, gN);
    k_scan_add<<<gN, 256, 0, stream>>>(partials, offs, cursor, N);
    k_scatter<<<gE, 256, 0, stream>>>(src, dst, cursor, sorted, E);

    // layer 1: project-then-aggregate (linearity of mean)
    k_gemm_dual<INDIM><<<N / 64, 256, 0, stream>>>(x, WT1l, WT1r, Pb, Q);
    k_agg<<<(N * 64 + 255) / 256, 256, 0, stream>>>(Pb, Q, b1l, offs, sorted, H, N, 1);

    // layer 2
    k_gemm_dual<HID><<<N / 64, 256, 0, stream>>>(H, WT2l, WT2r, Pb, Q);
    k_agg<<<(N * 64 + 255) / 256, 256, 0, stream>>>(Pb, Q, b2l, offs, sorted, zout, N, 0);
}